// Round 1
// baseline (637.854 us; speedup 1.0000x reference)
//
#include <hip/hip_runtime.h>

#define NB 128
#define LL 512
#define DD 768
#define JJ 32
#define SS 33
#define DM 200

// ---------------------------------------------------------------------------
// Fused per-segment score + softmax + weighted pooling.
// One block per (b, s). Two passes over the segment's tokens (2nd pass L2-hot).
// ---------------------------------------------------------------------------
__global__ __launch_bounds__(256) void pool_kernel(
    const float* __restrict__ hidden, const int* __restrict__ clause,
    const float* __restrict__ fc5w, float* __restrict__ pooled)
{
  int blk = blockIdx.x;          // b*33 + s
  int b = blk / SS;
  int s = blk - b * SS;
  int t0 = (s == 0) ? 0 : clause[b * JJ + s - 1];
  int t1 = (s == JJ) ? LL : clause[b * JJ + s];
  int nt = t1 - t0;
  if (nt > 64) nt = 64;          // data guarantees nt <= ~48
  if (nt < 1) nt = 1;

  __shared__ float wsm[64];
  int tid = threadIdx.x;
  int wave = tid >> 6, lane = tid & 63;

  // phase 1: attention scores = hidden . fc5_w  (bias is softmax-invariant)
  for (int t = t0 + wave; t < t0 + nt; t += 4) {
    const float* hp = hidden + ((long long)b * LL + t) * DD;
    float acc = 0.f;
#pragma unroll
    for (int d = lane; d < DD; d += 64) acc += hp[d] * fc5w[d];
#pragma unroll
    for (int off = 32; off; off >>= 1) acc += __shfl_xor(acc, off);
    if (lane == 0) wsm[t - t0] = acc;
  }
  __syncthreads();

  // phase 2: softmax over the segment (single wave)
  if (wave == 0) {
    float v = (lane < nt) ? wsm[lane] : -__builtin_inff();
    float mx = v;
#pragma unroll
    for (int off = 32; off; off >>= 1) mx = fmaxf(mx, __shfl_xor(mx, off));
    float e = (lane < nt) ? __expf(v - mx) : 0.f;
    float sm = e;
#pragma unroll
    for (int off = 32; off; off >>= 1) sm += __shfl_xor(sm, off);
    if (lane < nt) wsm[lane] = e / sm;
  }
  __syncthreads();

  // phase 3: pooled[b,s,:] = sum_t w[t] * hidden[b,t,:]
  float* op = pooled + (long long)blk * DD;
#pragma unroll
  for (int d = tid; d < DD; d += 256) {
    const float* hp = hidden + ((long long)b * LL + t0) * DD + d;
    float acc = 0.f;
    for (int t = 0; t < nt; ++t) acc += wsm[t] * hp[(long long)t * DD];
    op[d] = acc;
  }
}

// ---------------------------------------------------------------------------
// Generic fp32 GEMM: C[m,n] = act( sum_k A[m,k] * B'(n,k) + bias[n] + res[m,n] )
// transB=1: B is W[N][K] (row-major weights, C = A @ W^T)
// transB=0: B is B[K][N] (row-major,        C = A @ B)
// Batched via blockIdx.z with element strides sA/sB/sC. 64x64 tile, 4x4 micro.
// ---------------------------------------------------------------------------
#define TM 64
#define TN 64
#define KC 32

__global__ __launch_bounds__(256) void gemm_kernel(
    const float* __restrict__ A, int lda, long long sA,
    const float* __restrict__ B, int ldb, long long sB, int transB,
    const float* __restrict__ bias,
    const float* __restrict__ res,
    float* __restrict__ C, int ldc, long long sC,
    int M, int N, int K, int relu)
{
  __shared__ __align__(16) float As[KC][TM + 4];   // [k][m], stride 68 (16B-aligned rows)
  __shared__ __align__(16) float Bs[KC][TN + 4];   // [k][n]
  const int tid = threadIdx.x;
  const int m0 = blockIdx.x * TM;
  const int n0 = blockIdx.y * TN;
  const int z = blockIdx.z;
  A += (long long)z * sA;
  B += (long long)z * sB;
  C += (long long)z * sC;
  const float* resp = res ? res + (long long)z * sC : (const float*)0;

  const int tn0 = (tid & 15) * 4;   // n micro base (coalesced stores)
  const int tm0 = (tid >> 4) * 4;   // m micro base
  float acc[4][4] = {{0.f}};

  for (int k0 = 0; k0 < K; k0 += KC) {
    __syncthreads();
    // ---- A tile: 64 rows x 32 k, float4 along k, store transposed ----
    {
      int q = tid;
#pragma unroll
      for (int it = 0; it < 2; ++it, q += 256) {
        int row = q >> 3;
        int kq = (q & 7) << 2;
        int gm = m0 + row, gk = k0 + kq;
        float4 v = make_float4(0.f, 0.f, 0.f, 0.f);
        if (gm < M) {
          const float* p = A + (long long)gm * lda + gk;
          if (gk + 3 < K) {
            v = *(const float4*)p;
          } else {
            if (gk + 0 < K) v.x = p[0];
            if (gk + 1 < K) v.y = p[1];
            if (gk + 2 < K) v.z = p[2];
          }
        }
        As[kq + 0][row] = v.x;
        As[kq + 1][row] = v.y;
        As[kq + 2][row] = v.z;
        As[kq + 3][row] = v.w;
      }
    }
    // ---- B tile ----
    if (transB) {
      int q = tid;
#pragma unroll
      for (int it = 0; it < 2; ++it, q += 256) {
        int row = q >> 3;
        int kq = (q & 7) << 2;
        int gn = n0 + row, gk = k0 + kq;
        float4 v = make_float4(0.f, 0.f, 0.f, 0.f);
        if (gn < N) {
          const float* p = B + (long long)gn * ldb + gk;
          if (gk + 3 < K) {
            v = *(const float4*)p;
          } else {
            if (gk + 0 < K) v.x = p[0];
            if (gk + 1 < K) v.y = p[1];
            if (gk + 2 < K) v.z = p[2];
          }
        }
        Bs[kq + 0][row] = v.x;
        Bs[kq + 1][row] = v.y;
        Bs[kq + 2][row] = v.z;
        Bs[kq + 3][row] = v.w;
      }
    } else {
      int q = tid;
#pragma unroll
      for (int it = 0; it < 2; ++it, q += 256) {
        int kk = q >> 4;
        int nq = (q & 15) << 2;
        int gk = k0 + kk, gn = n0 + nq;
        float4 v = make_float4(0.f, 0.f, 0.f, 0.f);
        if (gk < K) {
          const float* p = B + (long long)gk * ldb + gn;
          if (gn + 3 < N) {
            v = *(const float4*)p;
          } else {
            if (gn + 0 < N) v.x = p[0];
            if (gn + 1 < N) v.y = p[1];
            if (gn + 2 < N) v.z = p[2];
          }
        }
        *(float4*)&Bs[kk][nq] = v;
      }
    }
    __syncthreads();
    // ---- compute: 2 x ds_read_b128 + 16 FMA per kk ----
#pragma unroll 8
    for (int kk = 0; kk < KC; ++kk) {
      float4 av = *(const float4*)&As[kk][tm0];
      float4 bv = *(const float4*)&Bs[kk][tn0];
      float ar[4] = {av.x, av.y, av.z, av.w};
      float br[4] = {bv.x, bv.y, bv.z, bv.w};
#pragma unroll
      for (int i = 0; i < 4; ++i)
#pragma unroll
        for (int j = 0; j < 4; ++j)
          acc[i][j] = fmaf(ar[i], br[j], acc[i][j]);
    }
  }

  // ---- epilogue: bias + residual + relu ----
#pragma unroll
  for (int i = 0; i < 4; ++i) {
    int gm = m0 + tm0 + i;
    if (gm >= M) continue;
#pragma unroll
    for (int j = 0; j < 4; ++j) {
      int gn = n0 + tn0 + j;
      if (gn >= N) continue;
      float v = acc[i][j];
      if (bias) v += bias[gn];
      if (resp) v += resp[(long long)gm * ldc + gn];
      if (relu) v = fmaxf(v, 0.f);
      C[(long long)gm * ldc + gn] = v;
    }
  }
}

// ---------------------------------------------------------------------------
// Softmax over 33 attention logits per row (scores laid out [4224][36]).
// Applies 1/sqrt(DM) scaling. One wave per row.
// ---------------------------------------------------------------------------
__global__ __launch_bounds__(256) void softmax33(float* __restrict__ sc)
{
  int row = blockIdx.x * 4 + (threadIdx.x >> 6);
  int lane = threadIdx.x & 63;
  if (row >= NB * SS) return;
  float* p = sc + (long long)row * 36;
  float v = (lane < SS) ? p[lane] * 0.07071067811865475f : -__builtin_inff();
  float mx = v;
#pragma unroll
  for (int off = 32; off; off >>= 1) mx = fmaxf(mx, __shfl_xor(mx, off));
  float e = (lane < SS) ? __expf(v - mx) : 0.f;
  float sm = e;
#pragma unroll
  for (int off = 32; off; off >>= 1) sm += __shfl_xor(sm, off);
  if (lane < SS) p[lane] = e / sm;
}

// ---------------------------------------------------------------------------
// LayerNorm over last dim (200), in place. One wave per row.
// ---------------------------------------------------------------------------
__global__ __launch_bounds__(256) void ln_kernel(
    float* __restrict__ x, const float* __restrict__ g,
    const float* __restrict__ bb, int nrows)
{
  int row = blockIdx.x * 4 + (threadIdx.x >> 6);
  int lane = threadIdx.x & 63;
  if (row >= nrows) return;
  float* p = x + (long long)row * DM;
  float vals[4];
  float s = 0.f;
#pragma unroll
  for (int i = 0; i < 4; ++i) {
    int k = lane + 64 * i;
    vals[i] = (k < DM) ? p[k] : 0.f;
    s += vals[i];
  }
#pragma unroll
  for (int off = 32; off; off >>= 1) s += __shfl_xor(s, off);
  float mean = s * (1.f / DM);
  float vs = 0.f;
#pragma unroll
  for (int i = 0; i < 4; ++i) {
    int k = lane + 64 * i;
    if (k < DM) { float d = vals[i] - mean; vs += d * d; }
  }
#pragma unroll
  for (int off = 32; off; off >>= 1) vs += __shfl_xor(vs, off);
  float rstd = rsqrtf(vs * (1.f / DM) + 1e-5f);
#pragma unroll
  for (int i = 0; i < 4; ++i) {
    int k = lane + 64 * i;
    if (k < DM) p[k] = (vals[i] - mean) * rstd * g[k] + bb[k];
  }
}

// ---------------------------------------------------------------------------
// Classifier: out[b,j,c] = [x[b,0,:], x[b,1+j,:]] . fc_w[c,:] + fc_b[c]
// One wave per (b, j).
// ---------------------------------------------------------------------------
__global__ __launch_bounds__(256) void cls_kernel(
    const float* __restrict__ x, const float* __restrict__ fcw,
    const float* __restrict__ fcb, float* __restrict__ out)
{
  int gw = blockIdx.x * 4 + (threadIdx.x >> 6);   // 0..4095 = b*32 + j
  int lane = threadIdx.x & 63;
  int b = gw >> 5, j = gw & 31;
  const float* x0 = x + (long long)(b * SS) * DM;
  const float* xj = x0 + (long long)(1 + j) * DM;
  float a0 = 0.f, a1 = 0.f;
  for (int k = lane; k < DM; k += 64) {
    float u = x0[k], w = xj[k];
    a0 += u * fcw[k]       + w * fcw[200 + k];
    a1 += u * fcw[400 + k] + w * fcw[600 + k];
  }
#pragma unroll
  for (int off = 32; off; off >>= 1) {
    a0 += __shfl_xor(a0, off);
    a1 += __shfl_xor(a1, off);
  }
  if (lane == 0) {
    out[gw * 2 + 0] = a0 + fcb[0];
    out[gw * 2 + 1] = a1 + fcb[1];
  }
}

// ---------------------------------------------------------------------------
extern "C" void kernel_launch(void* const* d_in, const int* in_sizes, int n_in,
                              void* d_out, int out_size, void* d_ws, size_t ws_size,
                              hipStream_t stream)
{
  (void)in_sizes; (void)n_in; (void)out_size; (void)ws_size;
  const float* hidden = (const float*)d_in[0];
  const int*   clause = (const int*)d_in[1];
  const float* fc5_w  = (const float*)d_in[2];
  // d_in[3] = fc5_b : softmax-invariant, unused
  const float* fc1_w  = (const float*)d_in[4];
  const float* fc1_b  = (const float*)d_in[5];
  const float* ain_w  = (const float*)d_in[6];
  const float* ain_b  = (const float*)d_in[7];
  const float* aout_w = (const float*)d_in[8];
  const float* aout_b = (const float*)d_in[9];
  const float* ln1_g  = (const float*)d_in[10];
  const float* ln1_b  = (const float*)d_in[11];
  const float* lin1_w = (const float*)d_in[12];
  const float* lin1_b = (const float*)d_in[13];
  const float* lin2_w = (const float*)d_in[14];
  const float* lin2_b = (const float*)d_in[15];
  const float* ln2_g  = (const float*)d_in[16];
  const float* ln2_b  = (const float*)d_in[17];
  const float* fc_w   = (const float*)d_in[18];
  const float* fc_b   = (const float*)d_in[19];
  float* out = (float*)d_out;

  const long long R = (long long)NB * SS;   // 4224 rows
  float* ws     = (float*)d_ws;
  float* pooled = ws;                       // R*768 = 3,244,032 floats
  float* x      = ws + R * DD;              // R*200
  float* att    = x + R * DM;               // R*200 (reused as ffn hidden)
  float* y      = att + R * DM;             // R*200
  float* scores = y + R * DM;               // 128*33*36 = 152,064
  float* qkv    = pooled;                   // R*600 <= R*768, pooled dead after fc1
  float* y2     = pooled;                   // qkv dead after SV

  // 1. ragged segment pooling
  pool_kernel<<<dim3(NB * SS), 256, 0, stream>>>(hidden, clause, fc5_w, pooled);
  // 2. x = pooled @ fc1_w^T + b            [4224 x 200], K=768
  gemm_kernel<<<dim3(66, 4, 1), 256, 0, stream>>>(pooled, DD, 0, fc1_w, DD, 0, 1,
      fc1_b, nullptr, x, DM, 0, (int)R, DM, DD, 0);
  // 3. qkv = x @ attn_in_w^T + b           [4224 x 600], K=200
  gemm_kernel<<<dim3(66, 10, 1), 256, 0, stream>>>(x, DM, 0, ain_w, DM, 0, 1,
      ain_b, nullptr, qkv, 600, 0, (int)R, 600, DM, 0);
  // 4. scores = Q @ K^T per batch          [33 x 33], K=200, batch 128
  gemm_kernel<<<dim3(1, 1, NB), 256, 0, stream>>>(qkv, 600, 19800, qkv + 200, 600, 19800, 1,
      nullptr, nullptr, scores, 36, 1188, SS, SS, DM, 0);
  // 5. softmax(scores / sqrt(DM))
  softmax33<<<dim3(1056), 256, 0, stream>>>(scores);
  // 6. att = S @ V per batch               [33 x 200], K=33
  gemm_kernel<<<dim3(1, 4, NB), 256, 0, stream>>>(scores, 36, 1188, qkv + 400, 600, 19800, 0,
      nullptr, nullptr, att, DM, 6600, SS, DM, SS, 0);
  // 7. y = x + att @ attn_out_w^T + b
  gemm_kernel<<<dim3(66, 4, 1), 256, 0, stream>>>(att, DM, 0, aout_w, DM, 0, 1,
      aout_b, x, y, DM, 0, (int)R, DM, DM, 0);
  // 8. LN1 (in place)
  ln_kernel<<<dim3(1056), 256, 0, stream>>>(y, ln1_g, ln1_b, (int)R);
  // 9. f1 = relu(y @ lin1_w^T + b)  -> att buffer
  gemm_kernel<<<dim3(66, 4, 1), 256, 0, stream>>>(y, DM, 0, lin1_w, DM, 0, 1,
      lin1_b, nullptr, att, DM, 0, (int)R, DM, DM, 1);
  // 10. y2 = y + f1 @ lin2_w^T + b
  gemm_kernel<<<dim3(66, 4, 1), 256, 0, stream>>>(att, DM, 0, lin2_w, DM, 0, 1,
      lin2_b, y, y2, DM, 0, (int)R, DM, DM, 0);
  // 11. LN2 (in place)
  ln_kernel<<<dim3(1056), 256, 0, stream>>>(y2, ln2_g, ln2_b, (int)R);
  // 12. classifier
  cls_kernel<<<dim3(1024), 256, 0, stream>>>(y2, fc_w, fc_b, out);
}

// Round 2
// 428.994 us; speedup vs baseline: 1.4869x; 1.4869x over previous
//
#include <hip/hip_runtime.h>

#define NB 128
#define LL 512
#define DD 768
#define JJ 32
#define SS 33
#define DM 200

typedef __attribute__((ext_vector_type(8))) short bf8_t;   // 8 bf16 (4 VGPRs)
typedef __attribute__((ext_vector_type(4))) float f4_t;    // MFMA C/D

static __device__ __forceinline__ unsigned short f2bf(float f) {
  unsigned u = __float_as_uint(f);
  return (unsigned short)((u + 0x7FFFu + ((u >> 16) & 1u)) >> 16);  // RNE
}

// ---------------------------------------------------------------------------
// Fused per-segment score + softmax + weighted pooling -> bf16 pooled.
// One block per (b, s). float4 throughout.
// ---------------------------------------------------------------------------
__global__ __launch_bounds__(256) void pool_kernel(
    const float* __restrict__ hidden, const int* __restrict__ clause,
    const float* __restrict__ fc5w, unsigned short* __restrict__ pooled_bf)
{
  int blk = blockIdx.x;          // b*33 + s
  int b = blk / SS;
  int s = blk - b * SS;
  int t0 = (s == 0) ? 0 : clause[b * JJ + s - 1];
  int t1 = (s == JJ) ? LL : clause[b * JJ + s];
  int nt = t1 - t0;
  if (nt > 64) nt = 64;
  if (nt < 1) nt = 1;

  __shared__ float wsm[64];
  int tid = threadIdx.x;
  int wave = tid >> 6, lane = tid & 63;

  // phase 1: scores = hidden . fc5_w  (bias softmax-invariant). float4 loads.
  const float4* w4 = (const float4*)fc5w;
  for (int t = t0 + wave; t < t0 + nt; t += 4) {
    const float4* hp = (const float4*)(hidden + ((long long)b * LL + t) * DD);
    float acc = 0.f;
#pragma unroll
    for (int i = 0; i < 3; ++i) {
      float4 h = hp[lane + 64 * i];
      float4 w = w4[lane + 64 * i];
      acc += h.x * w.x + h.y * w.y + h.z * w.z + h.w * w.w;
    }
#pragma unroll
    for (int off = 32; off; off >>= 1) acc += __shfl_xor(acc, off);
    if (lane == 0) wsm[t - t0] = acc;
  }
  __syncthreads();

  // phase 2: softmax over segment (single wave)
  if (wave == 0) {
    float v = (lane < nt) ? wsm[lane] : -__builtin_inff();
    float mx = v;
#pragma unroll
    for (int off = 32; off; off >>= 1) mx = fmaxf(mx, __shfl_xor(mx, off));
    float e = (lane < nt) ? __expf(v - mx) : 0.f;
    float sm = e;
#pragma unroll
    for (int off = 32; off; off >>= 1) sm += __shfl_xor(sm, off);
    if (lane < nt) wsm[lane] = e / sm;
  }
  __syncthreads();

  // phase 3: pooled[b,s,:] = sum_t w[t] * hidden[b,t,:]  (float4, 192 lanes)
  if (tid < 192) {
    const float4* base = (const float4*)(hidden + ((long long)b * LL + t0) * DD);
    float4 acc = make_float4(0.f, 0.f, 0.f, 0.f);
#pragma unroll 2
    for (int t = 0; t < nt; ++t) {
      float w = wsm[t];
      float4 h = base[t * 192 + tid];
      acc.x = fmaf(w, h.x, acc.x); acc.y = fmaf(w, h.y, acc.y);
      acc.z = fmaf(w, h.z, acc.z); acc.w = fmaf(w, h.w, acc.w);
    }
    ushort4 o;
    o.x = f2bf(acc.x); o.y = f2bf(acc.y); o.z = f2bf(acc.z); o.w = f2bf(acc.w);
    *(ushort4*)(pooled_bf + (long long)blk * DD + tid * 4) = o;
  }
}

// ---------------------------------------------------------------------------
// Convert + pad all weights fp32 -> bf16 (N padded to 16, K padded to 32).
// fc1: [208][768]  ain: [608][224]  aout/lin1/lin2: [208][224]
// ---------------------------------------------------------------------------
__global__ __launch_bounds__(256) void convert_w(
    const float* __restrict__ fc1_w, const float* __restrict__ ain_w,
    const float* __restrict__ aout_w, const float* __restrict__ lin1_w,
    const float* __restrict__ lin2_w,
    unsigned short* __restrict__ fc1_wb, unsigned short* __restrict__ ain_wb,
    unsigned short* __restrict__ aout_wb, unsigned short* __restrict__ lin1_wb,
    unsigned short* __restrict__ lin2_wb)
{
  int t = blockIdx.x * 256 + threadIdx.x;
  if (t < 208 * 768) {
    int n = t / 768, k = t - n * 768;
    fc1_wb[t] = f2bf((n < 200) ? fc1_w[n * 768 + k] : 0.f);
    return;
  }
  t -= 208 * 768;
  if (t < 608 * 224) {
    int n = t / 224, k = t - n * 224;
    ain_wb[t] = f2bf((n < 600 && k < 200) ? ain_w[n * 200 + k] : 0.f);
    return;
  }
  t -= 608 * 224;
  if (t < 208 * 224) {
    int n = t / 224, k = t - n * 224;
    aout_wb[t] = f2bf((n < 200 && k < 200) ? aout_w[n * 200 + k] : 0.f);
    return;
  }
  t -= 208 * 224;
  if (t < 208 * 224) {
    int n = t / 224, k = t - n * 224;
    lin1_wb[t] = f2bf((n < 200 && k < 200) ? lin1_w[n * 200 + k] : 0.f);
    return;
  }
  t -= 208 * 224;
  if (t < 208 * 224) {
    int n = t / 224, k = t - n * 224;
    lin2_wb[t] = f2bf((n < 200 && k < 200) ? lin2_w[n * 200 + k] : 0.f);
  }
}

// ---------------------------------------------------------------------------
// bf16 MFMA GEMM: C = act(A @ W^T + bias + res). One 16x16 tile per wave,
// fragments loaded directly from global (both operands row-major contiguous).
// M % 16 == 0, K % 32 == 0 (pre-padded), Npad % 16 == 0.
// ---------------------------------------------------------------------------
__global__ __launch_bounds__(256) void mfma_gemm(
    const unsigned short* __restrict__ A, int lda,
    const unsigned short* __restrict__ W, int ldw,
    const float* __restrict__ bias, const float* __restrict__ res,
    float* __restrict__ C, int ldc,
    unsigned short* __restrict__ Cb, int ldcb,
    int N, int K, int relu, int ntiles)
{
  int gw = blockIdx.x * 4 + (threadIdx.x >> 6);
  int lane = threadIdx.x & 63;
  int mt = gw / ntiles, nt = gw - mt * ntiles;
  int m0 = mt * 16, n0 = nt * 16;
  int col = lane & 15, quad = lane >> 4;
  int koff = quad * 8;

  const bf8_t* pa = (const bf8_t*)(A + (long long)(m0 + col) * lda + koff);
  const bf8_t* pw = (const bf8_t*)(W + (long long)(n0 + col) * ldw + koff);

  f4_t acc = {0.f, 0.f, 0.f, 0.f};
  int S = K >> 5;
  bf8_t a = pa[0], w = pw[0];
  for (int s = 1; s < S; ++s) {
    bf8_t a2 = pa[4 * s], w2 = pw[4 * s];
    acc = __builtin_amdgcn_mfma_f32_16x16x32_bf16(a, w, acc, 0, 0, 0);
    a = a2; w = w2;
  }
  acc = __builtin_amdgcn_mfma_f32_16x16x32_bf16(a, w, acc, 0, 0, 0);

  // epilogue: C/D layout col=lane&15, row=quad*4+r
  int gn = n0 + col;
  float bv = (bias && gn < N) ? bias[gn] : 0.f;
#pragma unroll
  for (int r = 0; r < 4; ++r) {
    int gm = m0 + quad * 4 + r;
    float v = acc[r] + bv;
    if (res && gn < N) v += res[(long long)gm * ldc + gn];
    if (relu) v = fmaxf(v, 0.f);
    if (C && gn < N) C[(long long)gm * ldc + gn] = v;
    if (Cb) Cb[(long long)gm * ldcb + gn] = f2bf(v);
  }
}

// ---------------------------------------------------------------------------
// Fused attention: per batch b: S = softmax(QK^T/sqrt(DM)), att = S @ V.
// Q,K in LDS; V streamed from global (L2-hot). Writes att fp32 + bf16(pad224).
// ---------------------------------------------------------------------------
__global__ __launch_bounds__(256) void attn_kernel(
    const float* __restrict__ qkv, float* __restrict__ att_f,
    unsigned short* __restrict__ att_b)
{
  __shared__ float shq[SS][DM];
  __shared__ float shk[SS][DM];
  __shared__ float sc[SS][SS + 1];
  int b = blockIdx.x, tid = threadIdx.x;
  const float* qkvg = qkv + (long long)b * SS * 600;

  for (int u = tid; u < SS * 50; u += 256) {
    int i = u / 50, c = u - i * 50;
    const float4* base = (const float4*)(qkvg + (long long)i * 600);
    ((float4*)&shq[i][0])[c] = base[c];
    ((float4*)&shk[i][0])[c] = base[50 + c];
  }
  __syncthreads();

  // scores: 1x4 j-blocking, float4 over k
  for (int g = tid; g < SS * 9; g += 256) {
    int i = g / 9, jg = g - i * 9;
    int j0 = jg * 4;
    int jj[4];
#pragma unroll
    for (int t = 0; t < 4; ++t) jj[t] = (j0 + t < SS) ? j0 + t : SS - 1;
    float s0 = 0.f, s1 = 0.f, s2 = 0.f, s3 = 0.f;
    for (int k = 0; k < DM; k += 4) {
      float4 qv = *(const float4*)&shq[i][k];
      float4 k0v = *(const float4*)&shk[jj[0]][k];
      float4 k1v = *(const float4*)&shk[jj[1]][k];
      float4 k2v = *(const float4*)&shk[jj[2]][k];
      float4 k3v = *(const float4*)&shk[jj[3]][k];
      s0 += qv.x * k0v.x + qv.y * k0v.y + qv.z * k0v.z + qv.w * k0v.w;
      s1 += qv.x * k1v.x + qv.y * k1v.y + qv.z * k1v.z + qv.w * k1v.w;
      s2 += qv.x * k2v.x + qv.y * k2v.y + qv.z * k2v.z + qv.w * k2v.w;
      s3 += qv.x * k3v.x + qv.y * k3v.y + qv.z * k3v.z + qv.w * k3v.w;
    }
    const float scale = 0.07071067811865475f;
    float sv[4] = {s0, s1, s2, s3};
#pragma unroll
    for (int t = 0; t < 4; ++t)
      if (j0 + t < SS) sc[i][j0 + t] = sv[t] * scale;
  }
  __syncthreads();

  // softmax rows
  if (tid < SS) {
    float mx = -__builtin_inff();
    for (int j = 0; j < SS; ++j) mx = fmaxf(mx, sc[tid][j]);
    float sm = 0.f;
    for (int j = 0; j < SS; ++j) { float e = __expf(sc[tid][j] - mx); sc[tid][j] = e; sm += e; }
    float inv = 1.f / sm;
    for (int j = 0; j < SS; ++j) sc[tid][j] *= inv;
  }
  __syncthreads();

  // att = S @ V (V from global, float4)
  for (int u = tid; u < SS * 50; u += 256) {
    int i = u / 50, d4 = u - i * 50;
    float4 acc = make_float4(0.f, 0.f, 0.f, 0.f);
#pragma unroll 3
    for (int j = 0; j < SS; ++j) {
      float w = sc[i][j];
      float4 v = *(const float4*)(qkvg + (long long)j * 600 + 400 + d4 * 4);
      acc.x = fmaf(w, v.x, acc.x); acc.y = fmaf(w, v.y, acc.y);
      acc.z = fmaf(w, v.z, acc.z); acc.w = fmaf(w, v.w, acc.w);
    }
    long long row = (long long)b * SS + i;
    *(float4*)(att_f + row * DM + d4 * 4) = acc;
    ushort4 o;
    o.x = f2bf(acc.x); o.y = f2bf(acc.y); o.z = f2bf(acc.z); o.w = f2bf(acc.w);
    *(ushort4*)(att_b + row * 224 + d4 * 4) = o;
  }
}

// ---------------------------------------------------------------------------
// LayerNorm(200) in place + optional bf16 mirror (stride 224).
// ---------------------------------------------------------------------------
__global__ __launch_bounds__(256) void ln_kernel(
    float* __restrict__ x, const float* __restrict__ g,
    const float* __restrict__ bb, unsigned short* __restrict__ ob, int nrows)
{
  int row = blockIdx.x * 4 + (threadIdx.x >> 6);
  int lane = threadIdx.x & 63;
  if (row >= nrows) return;
  float* p = x + (long long)row * DM;
  float vals[4];
  float s = 0.f;
#pragma unroll
  for (int i = 0; i < 4; ++i) {
    int k = lane + 64 * i;
    vals[i] = (k < DM) ? p[k] : 0.f;
    s += vals[i];
  }
#pragma unroll
  for (int off = 32; off; off >>= 1) s += __shfl_xor(s, off);
  float mean = s * (1.f / DM);
  float vs = 0.f;
#pragma unroll
  for (int i = 0; i < 4; ++i) {
    int k = lane + 64 * i;
    if (k < DM) { float d = vals[i] - mean; vs += d * d; }
  }
#pragma unroll
  for (int off = 32; off; off >>= 1) vs += __shfl_xor(vs, off);
  float rstd = rsqrtf(vs * (1.f / DM) + 1e-5f);
#pragma unroll
  for (int i = 0; i < 4; ++i) {
    int k = lane + 64 * i;
    if (k < DM) {
      float o = (vals[i] - mean) * rstd * g[k] + bb[k];
      p[k] = o;
      if (ob) ob[(long long)row * 224 + k] = f2bf(o);
    }
  }
}

// ---------------------------------------------------------------------------
// Classifier
// ---------------------------------------------------------------------------
__global__ __launch_bounds__(256) void cls_kernel(
    const float* __restrict__ x, const float* __restrict__ fcw,
    const float* __restrict__ fcb, float* __restrict__ out)
{
  int gw = blockIdx.x * 4 + (threadIdx.x >> 6);   // b*32 + j
  int lane = threadIdx.x & 63;
  int b = gw >> 5, j = gw & 31;
  const float* x0 = x + (long long)(b * SS) * DM;
  const float* xj = x0 + (long long)(1 + j) * DM;
  float a0 = 0.f, a1 = 0.f;
  for (int k = lane; k < DM; k += 64) {
    float u = x0[k], w = xj[k];
    a0 += u * fcw[k]       + w * fcw[200 + k];
    a1 += u * fcw[400 + k] + w * fcw[600 + k];
  }
#pragma unroll
  for (int off = 32; off; off >>= 1) {
    a0 += __shfl_xor(a0, off);
    a1 += __shfl_xor(a1, off);
  }
  if (lane == 0) {
    out[gw * 2 + 0] = a0 + fcb[0];
    out[gw * 2 + 1] = a1 + fcb[1];
  }
}

// ---------------------------------------------------------------------------
extern "C" void kernel_launch(void* const* d_in, const int* in_sizes, int n_in,
                              void* d_out, int out_size, void* d_ws, size_t ws_size,
                              hipStream_t stream)
{
  (void)in_sizes; (void)n_in; (void)out_size; (void)ws_size;
  const float* hidden = (const float*)d_in[0];
  const int*   clause = (const int*)d_in[1];
  const float* fc5_w  = (const float*)d_in[2];
  const float* fc1_w  = (const float*)d_in[4];
  const float* fc1_b  = (const float*)d_in[5];
  const float* ain_w  = (const float*)d_in[6];
  const float* ain_b  = (const float*)d_in[7];
  const float* aout_w = (const float*)d_in[8];
  const float* aout_b = (const float*)d_in[9];
  const float* ln1_g  = (const float*)d_in[10];
  const float* ln1_b  = (const float*)d_in[11];
  const float* lin1_w = (const float*)d_in[12];
  const float* lin1_b = (const float*)d_in[13];
  const float* lin2_w = (const float*)d_in[14];
  const float* lin2_b = (const float*)d_in[15];
  const float* ln2_g  = (const float*)d_in[16];
  const float* ln2_b  = (const float*)d_in[17];
  const float* fc_w   = (const float*)d_in[18];
  const float* fc_b   = (const float*)d_in[19];
  float* out = (float*)d_out;

  const long long R = (long long)NB * SS;   // 4224
  char* w8 = (char*)d_ws;
  // region 0: pooled_bf (6,488,064 B) ; aliased later by att_f32 + att_bf
  unsigned short* pooled_bf = (unsigned short*)(w8 + 0);
  float*          att_f32   = (float*)(w8 + 0);                       // 3,379,200
  unsigned short* att_bf    = (unsigned short*)(w8 + 3379200);        // 1,892,352
  // region 1: x_f32
  float*          x_f32     = (float*)(w8 + 6488064);                 // 3,379,200
  // region 2: x_bf (= y_bf)
  unsigned short* x_bf      = (unsigned short*)(w8 + 9867264);        // 1,892,352
  unsigned short* y_bf      = x_bf;
  // region 3: qkv_f32 (10,137,600) ; aliased later by y_f32 + f1_bf + y2_f32
  float*          qkv_f32   = (float*)(w8 + 11759616);
  float*          y_f32     = (float*)(w8 + 11759616);                // 3,379,200
  unsigned short* f1_bf     = (unsigned short*)(w8 + 15138816);       // 1,892,352
  float*          y2_f32    = (float*)(w8 + 17031168);                // 3,379,200
  // region 4: weights bf16
  unsigned short* fc1_wb  = (unsigned short*)(w8 + 21897216);         // 319,488
  unsigned short* ain_wb  = (unsigned short*)(w8 + 22216704);         // 272,384
  unsigned short* aout_wb = (unsigned short*)(w8 + 22489088);         //  93,184
  unsigned short* lin1_wb = (unsigned short*)(w8 + 22582272);
  unsigned short* lin2_wb = (unsigned short*)(w8 + 22675456);         // end 22,768,640

  // pad-zero x_bf (also serves y_bf later)
  hipMemsetAsync(x_bf, 0, R * 224 * 2, stream);
  convert_w<<<dim3(1702), 256, 0, stream>>>(fc1_w, ain_w, aout_w, lin1_w, lin2_w,
      fc1_wb, ain_wb, aout_wb, lin1_wb, lin2_wb);
  // 1. ragged segment pooling -> bf16
  pool_kernel<<<dim3(NB * SS), 256, 0, stream>>>(hidden, clause, fc5_w, pooled_bf);
  // 2. x = pooled @ fc1_w^T + b   (fp32 + bf16)
  mfma_gemm<<<dim3(858), 256, 0, stream>>>(pooled_bf, DD, fc1_wb, DD, fc1_b,
      nullptr, x_f32, DM, x_bf, 224, DM, DD, 0, 13);
  // pooled dead -> zero att_bf pad region
  hipMemsetAsync(att_bf, 0, R * 224 * 2, stream);
  // 3. qkv = x @ ain_w^T + b   (fp32 only)
  mfma_gemm<<<dim3(2508), 256, 0, stream>>>(x_bf, 224, ain_wb, 224, ain_b,
      nullptr, qkv_f32, 600, nullptr, 0, 600, 224, 0, 38);
  // 4. fused attention -> att fp32 + bf16
  attn_kernel<<<dim3(NB), 256, 0, stream>>>(qkv_f32, att_f32, att_bf);
  // qkv dead -> zero f1_bf pad region
  hipMemsetAsync(f1_bf, 0, R * 224 * 2, stream);
  // 5. y = x + att @ aout_w^T + b
  mfma_gemm<<<dim3(858), 256, 0, stream>>>(att_bf, 224, aout_wb, 224, aout_b,
      x_f32, y_f32, DM, nullptr, 0, DM, 224, 0, 13);
  // 6. LN1 (in place) + bf16 mirror
  ln_kernel<<<dim3(1056), 256, 0, stream>>>(y_f32, ln1_g, ln1_b, y_bf, (int)R);
  // 7. f1 = relu(y @ lin1_w^T + b)  (bf16 only)
  mfma_gemm<<<dim3(858), 256, 0, stream>>>(y_bf, 224, lin1_wb, 224, lin1_b,
      nullptr, nullptr, DM, f1_bf, 224, DM, 224, 1, 13);
  // 8. y2 = y + f1 @ lin2_w^T + b
  mfma_gemm<<<dim3(858), 256, 0, stream>>>(f1_bf, 224, lin2_wb, 224, lin2_b,
      y_f32, y2_f32, DM, nullptr, 0, DM, 224, 0, 13);
  // 9. LN2 (in place)
  ln_kernel<<<dim3(1056), 256, 0, stream>>>(y2_f32, ln2_g, ln2_b, nullptr, (int)R);
  // 10. classifier
  cls_kernel<<<dim3(1024), 256, 0, stream>>>(y2_f32, fc_w, fc_b, out);
}